// Round 11
// baseline (29.020 us; speedup 1.0000x reference)
//
#include <hip/hip_runtime.h>

#define BB 4
#define SS 8192
#define DD 1024
#define TPB 1024
#define GROUP 64          // output rows per block (4 per wave)
#define LPL 128           // boundary elements per lane (SS / 64)

typedef float vf4 __attribute__((ext_vector_type(4)));

// (r+1)-th set bit index in w (r 0-based); pure arithmetic, any r is safe.
__device__ __forceinline__ int nth_set_u32(unsigned int w, int r) {
    int p = 0;
    #pragma unroll
    for (int step = 16; step >= 1; step >>= 1) {
        const unsigned int lm = (p + step >= 32) ? 0xFFFFFFFFu : ((1u << (p + step)) - 1u);
        if (__popc(w & lm) <= r) p += step;
    }
    return p;
}

__device__ __forceinline__ int nth_set_128(unsigned int m0, unsigned int m1,
                                           unsigned int m2, unsigned int m3, int r) {
    const int c0 = __popc(m0), c1 = __popc(m1), c2 = __popc(m2);
    unsigned int w; int base;
    if (r < c0)                { w = m0; base = 0; }
    else if (r < c0 + c1)      { w = m1; base = 32; r -= c0; }
    else if (r < c0 + c1 + c2) { w = m2; base = 64; r -= c0 + c1; }
    else                       { w = m3; base = 96; r -= c0 + c1 + c2; }
    return base + nth_set_u32(w, r);
}

// Zero-barrier kernel: each wave independently recomputes the full per-batch
// stable-partition scan in registers (128 boundary elems per lane) and
// resolves its 4 output rows via ballot + nth-set-bit + shuffle. No LDS.
__global__ __launch_bounds__(TPB) void chunk_block(const void* __restrict__ bptr,
                                                   const float* __restrict__ x,
                                                   float* __restrict__ out,
                                                   float* __restrict__ ntok,
                                                   int max_chunks, int ngroups) {
    const int b = blockIdx.x / ngroups;
    const int g = blockIdx.x % ngroups;
    const int row0 = g * GROUP;
    const int t = threadIdx.x;
    const int lane = t & 63;
    const int wave = t >> 6;

    // ---- wave-local dtype detect (1 KB window): 0=int32, 1=byte-bool, 2=float32
    int f;
    {
        const uint4* __restrict__ wp = (const uint4*)bptr;
        uint4 w = wp[lane];
        unsigned int o = w.x | w.y | w.z | w.w;
        const bool non = __any((o & 0xFEFEFEFEu) != 0u);
        const bool mis = __any((o & 0xFFFFFF00u) != 0u);
        f = non ? 2 : (mis ? 1 : 0);
    }

    // ---- this lane's 128 contiguous boundary elements -> 128-bit mask
    unsigned int m0 = 0, m1 = 0, m2 = 0, m3 = 0;
    if (f == 1) {
        const uint4* __restrict__ p =
            (const uint4*)((const unsigned char*)bptr + b * SS + lane * LPL);
        unsigned int mm[4] = {0, 0, 0, 0};
        #pragma unroll
        for (int r8 = 0; r8 < 8; ++r8) {
            uint4 w = p[r8];
            unsigned int ws[4] = {w.x, w.y, w.z, w.w};
            unsigned int bits16 = 0;
            #pragma unroll
            for (int q = 0; q < 4; ++q) {
                unsigned int v = ws[q];
                unsigned int tt = v | (v >> 4); tt |= tt >> 2; tt |= tt >> 1;
                const unsigned int nib = (((tt & 0x01010101u) * 0x01020408u) >> 24) & 0xFu;
                bits16 |= nib << (q * 4);
            }
            mm[r8 >> 1] |= bits16 << ((r8 & 1) * 16);
        }
        m0 = mm[0]; m1 = mm[1]; m2 = mm[2]; m3 = mm[3];
    } else if (f == 0) {
        const uint4* __restrict__ p = (const uint4*)((const int*)bptr + b * SS + lane * LPL);
        unsigned int mm[4] = {0, 0, 0, 0};
        #pragma unroll
        for (int r4 = 0; r4 < 32; ++r4) {
            uint4 w = p[r4];
            const unsigned int nib = (unsigned int)((w.x != 0) | ((w.y != 0) << 1) |
                                                    ((w.z != 0) << 2) | ((w.w != 0) << 3));
            mm[r4 >> 3] |= nib << ((r4 & 7) * 4);
        }
        m0 = mm[0]; m1 = mm[1]; m2 = mm[2]; m3 = mm[3];
    } else {
        const float4* __restrict__ p =
            (const float4*)((const float*)bptr + b * SS + lane * LPL);
        unsigned int mm[4] = {0, 0, 0, 0};
        #pragma unroll
        for (int r4 = 0; r4 < 32; ++r4) {
            float4 w = p[r4];
            const unsigned int nib = (unsigned int)((w.x != 0.0f) | ((w.y != 0.0f) << 1) |
                                                    ((w.z != 0.0f) << 2) | ((w.w != 0.0f) << 3));
            mm[r4 >> 3] |= nib << ((r4 & 7) * 4);
        }
        m0 = mm[0]; m1 = mm[1]; m2 = mm[2]; m3 = mm[3];
    }

    // ---- wave scan: exclusive true-prefix per lane + total
    const int cnt = __popc(m0) + __popc(m1) + __popc(m2) + __popc(m3);
    int scan = cnt;
    #pragma unroll
    for (int o = 1; o < 64; o <<= 1) {
        int n = __shfl_up(scan, o, 64);
        if (lane >= o) scan += n;
    }
    const int tb = scan - cnt;           // trues before this lane's range
    const int T = __shfl(scan, 63);      // total trues in batch
    const int fb = lane * LPL - tb;      // falses before this lane's range

    if (g == 0 && t == 0) ntok[b] = (float)T;

    // ---- resolve this wave's 4 source rows (wave-uniform branches)
    const vf4* src[4];
    vf4* dst[4];
    bool valid[4];
    #pragma unroll
    for (int r = 0; r < 4; ++r) {
        const int c = row0 + wave * 4 + r;
        valid[r] = c < max_chunks;
        const int cc = valid[r] ? c : 0;
        int j;
        if (cc < T) {
            const int rk = cc;
            const bool own = (tb <= rk) && (rk < tb + cnt);
            const unsigned long long bal = __ballot(own);
            const int owner = __ffsll((unsigned long long)bal) - 1;
            const int jl = lane * LPL + nth_set_128(m0, m1, m2, m3, rk - tb);
            j = __shfl(jl, owner);
        } else {
            const int rk = cc - T;
            const bool own = (fb <= rk) && (rk < fb + (LPL - cnt));
            const unsigned long long bal = __ballot(own);
            const int owner = __ffsll((unsigned long long)bal) - 1;
            const int jl = lane * LPL + nth_set_128(~m0, ~m1, ~m2, ~m3, rk - fb);
            j = __shfl(jl, owner);
        }
        src[r] = (const vf4*)(x + ((long long)b * SS + j) * DD);
        dst[r] = (vf4*)(out + ((long long)b * max_chunks + cc) * (long long)DD);
    }

    // ---- copy: 16 float4 loads in flight, then 16 stores
    vf4 v[4][4];
    #pragma unroll
    for (int r = 0; r < 4; ++r)
        #pragma unroll
        for (int q = 0; q < 4; ++q)
            v[r][q] = src[r][lane + 64 * q];
    #pragma unroll
    for (int r = 0; r < 4; ++r)
        if (valid[r])
            #pragma unroll
            for (int q = 0; q < 4; ++q)
                dst[r][lane + 64 * q] = v[r][q];
}

extern "C" void kernel_launch(void* const* d_in, const int* in_sizes, int n_in,
                              void* d_out, int out_size, void* d_ws, size_t ws_size,
                              hipStream_t stream) {
    const float* x = (const float*)d_in[0];
    const void* bptr = d_in[1];
    float* out = (float*)d_out;

    const int max_chunks = (out_size - BB) / (BB * DD);
    const int ngroups = (max_chunks + GROUP - 1) / GROUP;
    float* ntok = out + (long long)BB * max_chunks * DD;

    chunk_block<<<BB * ngroups, TPB, 0, stream>>>(bptr, x, out, ntok, max_chunks, ngroups);
}

// Round 12
// 16.893 us; speedup vs baseline: 1.7179x; 1.7179x over previous
//
#include <hip/hip_runtime.h>

#define BB 4
#define SS 8192
#define DD 1024
#define TPB 1024
#define GROUP 64          // output rows per block (4 per wave)

typedef float vf4 __attribute__((ext_vector_type(4)));

// R10 structure (best measured: 18.1 us) + non-temporal output stores:
//  - wave-local dtype detect (1 KB window, no barrier)
//  - parallel cross-wave scan combine (one barrier)
//  - LDS scatter of the block's 64 source rows (one barrier)
//  - copy: cached loads (x is L2/L3-hot), nt stores (don't pollute L2).
__global__ __launch_bounds__(TPB) void chunk_block(const void* __restrict__ bptr,
                                                   const float* __restrict__ x,
                                                   float* __restrict__ out,
                                                   float* __restrict__ ntok,
                                                   int max_chunks, int ngroups) {
    const int b = blockIdx.x / ngroups;
    const int g = blockIdx.x % ngroups;
    const int row0 = g * GROUP;
    const int t = threadIdx.x;
    const int lane = t & 63;
    const int wave = t >> 6;

    // ---- wave-local dtype detect: 0=int32, 1=byte-bool, 2=float32 ----
    int f;
    {
        const uint4* __restrict__ wp = (const uint4*)bptr;
        uint4 w = wp[lane];                       // bytes [0, 1024)
        unsigned int o = w.x | w.y | w.z | w.w;
        const bool non = __any((o & 0xFEFEFEFEu) != 0u);  // any byte > 1 -> float32
        const bool mis = __any((o & 0xFFFFFF00u) != 0u);  // misaligned nonzero -> bool
        f = non ? 2 : (mis ? 1 : 0);
    }

    // ---- boundaries: 8 elements per thread -> bitmask ----
    unsigned int mask = 0;
    if (f == 0) {
        const int4* __restrict__ p = (const int4*)((const int*)bptr + b * SS);
        int4 w0 = p[t * 2], w1 = p[t * 2 + 1];
        int vi[8] = {w0.x, w0.y, w0.z, w0.w, w1.x, w1.y, w1.z, w1.w};
        #pragma unroll
        for (int k = 0; k < 8; ++k) mask |= (unsigned int)(vi[k] != 0) << k;
    } else if (f == 1) {
        const uint2* __restrict__ p = (const uint2*)((const unsigned char*)bptr + b * SS);
        uint2 w = p[t];
        unsigned int ws[2] = {w.x, w.y};
        #pragma unroll
        for (int k = 0; k < 8; ++k)
            mask |= (unsigned int)(((ws[k >> 2] >> ((k & 3) * 8)) & 0xFFu) != 0u) << k;
    } else {
        const float4* __restrict__ p = (const float4*)((const float*)bptr + b * SS);
        float4 w0 = p[t * 2], w1 = p[t * 2 + 1];
        float vf[8] = {w0.x, w0.y, w0.z, w0.w, w1.x, w1.y, w1.z, w1.w};
        #pragma unroll
        for (int k = 0; k < 8; ++k) mask |= (unsigned int)(vf[k] != 0.0f) << k;
    }
    const int cnt = __popc(mask);

    // ---- wave inclusive scan ----
    int scan = cnt;
    #pragma unroll
    for (int o = 1; o < 64; o <<= 1) {
        int n = __shfl_up(scan, o, 64);
        if (lane >= o) scan += n;
    }

    // ---- parallel cross-wave combine (one barrier, no serial stage) ----
    __shared__ int waveTot[16];
    __shared__ int s_rowj[GROUP];
    if (lane == 63) waveTot[wave] = scan;
    __syncthreads();
    int waveOff = 0, T = 0;
    #pragma unroll
    for (int w = 0; w < 16; ++w) {
        const int wt = waveTot[w];
        waveOff += (w < wave) ? wt : 0;
        T += wt;
    }

    // ---- dests; capture the GROUP source rows this block owns ----
    int tr = waveOff + (scan - cnt);   // exclusive prefix of trues
    #pragma unroll
    for (int k = 0; k < 8; ++k) {
        const int j = t * 8 + k;
        int dest;
        if ((mask >> k) & 1u) { dest = tr; tr++; }
        else                  { dest = T + (j - tr); }
        const int rel = dest - row0;
        if ((unsigned)rel < (unsigned)GROUP) s_rowj[rel] = j;
    }
    if (g == 0 && t == 0) ntok[b] = (float)T;
    __syncthreads();

    // ---- copy: each of 16 waves moves 4 rows; cached loads, nt stores ----
    const int rbase = wave * 4;
    const vf4* src[4];
    vf4* dst[4];
    bool valid[4];
    #pragma unroll
    for (int r = 0; r < 4; ++r) {
        const int c = row0 + rbase + r;
        valid[r] = c < max_chunks;
        const int cc = valid[r] ? c : 0;
        const int j = s_rowj[valid[r] ? (rbase + r) : 0];
        src[r] = (const vf4*)(x + ((long long)b * SS + j) * DD);
        dst[r] = (vf4*)(out + ((long long)b * max_chunks + cc) * (long long)DD);
    }
    vf4 v[4][4];
    #pragma unroll
    for (int r = 0; r < 4; ++r)
        #pragma unroll
        for (int q = 0; q < 4; ++q)
            v[r][q] = src[r][lane + 64 * q];
    #pragma unroll
    for (int r = 0; r < 4; ++r)
        if (valid[r])
            #pragma unroll
            for (int q = 0; q < 4; ++q)
                __builtin_nontemporal_store(v[r][q], &dst[r][lane + 64 * q]);
}

extern "C" void kernel_launch(void* const* d_in, const int* in_sizes, int n_in,
                              void* d_out, int out_size, void* d_ws, size_t ws_size,
                              hipStream_t stream) {
    const float* x = (const float*)d_in[0];
    const void* bptr = d_in[1];
    float* out = (float*)d_out;

    const int max_chunks = (out_size - BB) / (BB * DD);
    const int ngroups = (max_chunks + GROUP - 1) / GROUP;
    float* ntok = out + (long long)BB * max_chunks * DD;

    chunk_block<<<BB * ngroups, TPB, 0, stream>>>(bptr, x, out, ntok, max_chunks, ngroups);
}